// Round 1
// baseline (227.592 us; speedup 1.0000x reference)
//
#include <hip/hip_runtime.h>
#include <math.h>

// Problem constants
#define B_N   4
#define CIN   21
#define HIDC  48
#define H0    81
#define NP    6561      // 81*81
#define HH    324
#define NPH   104976    // 324*324

// ---------------------------------------------------------------------------
// K1: conv1 for BOTH heads (21 -> 48, relu). 96 total output channels split
// into 6 groups of 16. Block = 256 threads = 16x16 pixel tile; x tile staged
// in LDS with zero padding (lax 'SAME'). Weight reads are wave-uniform
// (scalar cache).
// ---------------------------------------------------------------------------
__global__ __launch_bounds__(256) void k1_conv1(
    const float* __restrict__ x,
    const float* __restrict__ w1o, const float* __restrict__ b1o,
    const float* __restrict__ w1g, const float* __restrict__ b1g,
    float* __restrict__ hid_o, float* __restrict__ hid_g)
{
    __shared__ float xs[CIN][18][18];
    const int tile = blockIdx.x;        // 0..35
    const int ocg  = blockIdx.y;        // 0..5
    const int b    = blockIdx.z;
    const int ty0 = (tile / 6) * 16, tx0 = (tile % 6) * 16;
    const int tid = threadIdx.x;
    const float* xb = x + (size_t)b * CIN * NP;
    for (int e = tid; e < CIN * 18 * 18; e += 256) {
        int ic = e / 324, r = e % 324, yy = r / 18, xx = r % 18;
        int gy = ty0 - 1 + yy, gx = tx0 - 1 + xx;
        float v = 0.f;
        if (gy >= 0 && gy < H0 && gx >= 0 && gx < H0) v = xb[ic * NP + gy * H0 + gx];
        xs[ic][yy][xx] = v;
    }
    __syncthreads();
    const int py = tid >> 4, px = tid & 15;
    const int oy = ty0 + py, ox = tx0 + px;
    const bool head_o = (ocg < 3);
    const float* w  = head_o ? w1o : w1g;
    const float* bb = head_o ? b1o : b1g;
    float* out      = head_o ? hid_o : hid_g;
    const int oc0 = (head_o ? ocg : ocg - 3) * 16;
    float acc[16];
    #pragma unroll
    for (int o = 0; o < 16; o++) acc[o] = bb[oc0 + o];
    for (int ic = 0; ic < CIN; ic++) {
        #pragma unroll
        for (int ky = 0; ky < 3; ky++) {
            #pragma unroll
            for (int kx = 0; kx < 3; kx++) {
                const float xv = xs[ic][py + ky][px + kx];
                const float* wp = w + (oc0 * CIN + ic) * 9 + ky * 3 + kx;
                #pragma unroll
                for (int o = 0; o < 16; o++)
                    acc[o] = fmaf(xv, wp[o * (CIN * 9)], acc[o]);
            }
        }
    }
    if (oy < H0 && ox < H0) {
        float* op = out + ((size_t)b * HIDC + oc0) * NP + oy * H0 + ox;
        #pragma unroll
        for (int o = 0; o < 16; o++) op[o * NP] = fmaxf(acc[o], 0.f);
    }
}

// ---------------------------------------------------------------------------
// K2: conv2 for both heads (48->8 and 48->1), then v=tanh, g=sigmoid, and the
// fused mask math. DIFF[d,0] == 0, so ker = sum_d (-v_d) * DT[d] / 8, with
// DT a fixed +-1 table (compile-time folded). Writes v to d_out; g, mask_lp,
// mask_hp to workspace. Block = 64 threads = 8x8 tile.
// ---------------------------------------------------------------------------
__global__ __launch_bounds__(64) void k2_conv2_masks(
    const float* __restrict__ hid_o, const float* __restrict__ hid_g,
    const float* __restrict__ w2o, const float* __restrict__ b2o,
    const float* __restrict__ w2g, const float* __restrict__ b2g,
    float* __restrict__ v_out,
    float* __restrict__ g_buf, float* __restrict__ m_lp, float* __restrict__ m_hp)
{
    __shared__ float so[HIDC][10][10];
    __shared__ float sg[HIDC][10][10];
    const int tile = blockIdx.x;   // 0..120
    const int b = blockIdx.y;
    const int ty0 = (tile / 11) * 8, tx0 = (tile % 11) * 8;
    const int tid = threadIdx.x;
    const float* ho = hid_o + (size_t)b * HIDC * NP;
    const float* hg = hid_g + (size_t)b * HIDC * NP;
    for (int e = tid; e < HIDC * 100; e += 64) {
        int ch = e / 100, r = e % 100, yy = r / 10, xx = r % 10;
        int gy = ty0 - 1 + yy, gx = tx0 - 1 + xx;
        bool in = (gy >= 0 && gy < H0 && gx >= 0 && gx < H0);
        int gidx = ch * NP + gy * H0 + gx;
        so[ch][yy][xx] = in ? ho[gidx] : 0.f;
        sg[ch][yy][xx] = in ? hg[gidx] : 0.f;
    }
    __syncthreads();
    const int py = tid >> 3, px = tid & 7;
    const int oy = ty0 + py, ox = tx0 + px;
    if (oy >= H0 || ox >= H0) return;
    float av[8];
    #pragma unroll
    for (int d = 0; d < 8; d++) av[d] = b2o[d];
    float ag = b2g[0];
    for (int ic = 0; ic < HIDC; ic++) {
        #pragma unroll
        for (int ky = 0; ky < 3; ky++) {
            #pragma unroll
            for (int kx = 0; kx < 3; kx++) {
                const float vo = so[ic][py + ky][px + kx];
                const float vg = sg[ic][py + ky][px + kx];
                const int wi = ic * 9 + ky * 3 + kx;
                #pragma unroll
                for (int d = 0; d < 8; d++)
                    av[d] = fmaf(vo, w2o[d * (HIDC * 9) + wi], av[d]);
                ag = fmaf(vg, w2g[wi], ag);
            }
        }
    }
    float v[8];
    #pragma unroll
    for (int d = 0; d < 8; d++) v[d] = tanhf(av[d]);   // VMAX = 1
    const int pix = oy * H0 + ox;
    #pragma unroll
    for (int d = 0; d < 8; d++) v_out[((size_t)b * 8 + d) * NP + pix] = v[d];
    const float g = 1.f / (1.f + expf(-ag));
    g_buf[(size_t)b * NP + pix] = g;

    // ker[n] = -(1/8) * sum_d v[d] * DT[d][n]; center (+2.5) at n=4
    constexpr float DT[8][9] = {
        {-1, 0, 1, -1, 0, 1, -1, 0, 1},
        {-1,-1, 0, -1, 0, 1,  0, 1, 1},
        {-1,-1,-1,  0, 0, 0,  1, 1, 1},
        { 0,-1,-1,  1, 0,-1,  1, 1, 0},
        { 1, 0,-1,  1, 0,-1,  1, 0,-1},
        { 1, 1, 0,  1, 0,-1,  0,-1,-1},
        { 1, 1, 1,  0, 0, 0, -1,-1,-1},
        { 0, 1, 1, -1, 0, 1, -1,-1, 0}};
    float ker[9];
    #pragma unroll
    for (int n = 0; n < 9; n++) {
        float s = 0.f;
        #pragma unroll
        for (int d = 0; d < 8; d++) s += v[d] * DT[d][n];
        ker[n] = -0.125f * s;
    }
    ker[4] += 2.5f;
    // softmax(ker / 0.5)
    float mx = ker[0];
    #pragma unroll
    for (int n = 1; n < 9; n++) mx = fmaxf(mx, ker[n]);
    float ex[9], sum = 0.f;
    #pragma unroll
    for (int n = 0; n < 9; n++) { ex[n] = expf((ker[n] - mx) * 2.0f); sum += ex[n]; }
    const float rs = 1.f / sum;
    #pragma unroll
    for (int n = 0; n < 9; n++) m_lp[((size_t)b * 9 + n) * NP + pix] = ex[n] * rs;
    // highpass: subtract mean, L1-normalize
    float mean = 0.f;
    #pragma unroll
    for (int n = 0; n < 9; n++) mean += ker[n];
    mean *= (1.f / 9.f);
    float den = 1e-8f;
    #pragma unroll
    for (int n = 0; n < 9; n++) den += fabsf(ker[n] - mean);
    const float rd = 1.f / den;
    #pragma unroll
    for (int n = 0; n < 9; n++) m_hp[((size_t)b * 9 + n) * NP + pix] = (ker[n] - mean) * rd;
}

// ---------------------------------------------------------------------------
// K3: low-res 9-tap aggregation (reflect padding), shared across the 4x4
// upsample blocks: agg_lp[c] = sum_n patch[n]*mask_lp[n], same for hp.
// ---------------------------------------------------------------------------
__global__ __launch_bounds__(64) void k3_agg(
    const float* __restrict__ x, const float* __restrict__ m_lp,
    const float* __restrict__ m_hp,
    float* __restrict__ a_lp, float* __restrict__ a_hp)
{
    __shared__ float xs[CIN][10][10];
    const int tile = blockIdx.x, b = blockIdx.y;
    const int ty0 = (tile / 11) * 8, tx0 = (tile % 11) * 8;
    const int tid = threadIdx.x;
    const float* xb = x + (size_t)b * CIN * NP;
    for (int e = tid; e < CIN * 100; e += 64) {
        int ic = e / 100, r = e % 100, yy = r / 10, xx = r % 10;
        int gy = ty0 - 1 + yy, gx = tx0 - 1 + xx;
        gy = gy < 0 ? -gy : (gy > H0 - 1 ? 2 * (H0 - 1) - gy : gy);
        gx = gx < 0 ? -gx : (gx > H0 - 1 ? 2 * (H0 - 1) - gx : gx);
        xs[ic][yy][xx] = xb[ic * NP + gy * H0 + gx];
    }
    __syncthreads();
    const int py = tid >> 3, px = tid & 7;
    const int oy = ty0 + py, ox = tx0 + px;
    if (oy >= H0 || ox >= H0) return;
    const int pix = oy * H0 + ox;
    float ml[9], mh[9];
    #pragma unroll
    for (int n = 0; n < 9; n++) {
        ml[n] = m_lp[((size_t)b * 9 + n) * NP + pix];
        mh[n] = m_hp[((size_t)b * 9 + n) * NP + pix];
    }
    for (int c = 0; c < CIN; c++) {
        float alp = 0.f, ahp = 0.f;
        #pragma unroll
        for (int ky = 0; ky < 3; ky++) {
            #pragma unroll
            for (int kx = 0; kx < 3; kx++) {
                const float p = xs[c][py + ky][px + kx];
                const int n = ky * 3 + kx;
                alp = fmaf(p, ml[n], alp);
                ahp = fmaf(p, mh[n], ahp);
            }
        }
        a_lp[((size_t)b * CIN + c) * NP + pix] = alp;
        a_hp[((size_t)b * CIN + c) * NP + pix] = ahp;
    }
}

// ---------------------------------------------------------------------------
// K4: hi-res blend. One thread = one float4 of output row (4 consecutive W).
// The repeat index W>>2 is constant within the float4 so agg/g/lam are
// per-thread scalars; only bilinear x_up varies. blockIdx.y==CIN writes g_up.
// 243 of 256 threads active (3 rows x 81 quads).
// ---------------------------------------------------------------------------
__global__ __launch_bounds__(256) void k4_up(
    const float* __restrict__ x, const float* __restrict__ g_buf,
    const float* __restrict__ a_lp, const float* __restrict__ a_hp,
    const float* __restrict__ beta,
    float* __restrict__ y_out, float* __restrict__ gup_out)
{
    const int tid = threadIdx.x;
    if (tid >= 243) return;
    const int c = blockIdx.y;              // 0..20 = channel, 21 = g_up
    const int b = blockIdx.z;
    const int H = blockIdx.x * 3 + tid / 81;
    const int wq = tid % 81;
    const int h0r = H >> 2;
    const float g = g_buf[(size_t)b * NP + h0r * H0 + wq];
    if (c == CIN) {
        *reinterpret_cast<float4*>(gup_out + (size_t)b * NPH + H * HH + wq * 4) =
            make_float4(g, g, g, g);
        return;
    }
    const float tb = tanhf(beta[0]);
    const float alp = a_lp[((size_t)b * CIN + c) * NP + h0r * H0 + wq];
    const float ahp = a_hp[((size_t)b * CIN + c) * NP + h0r * H0 + wq];
    const float lam = 0.15f * (1.f - g);
    const float gh = tb * g;
    const float* xc = x + ((size_t)b * CIN + c) * NP;
    const float ysf = (float)H * (80.f / 323.f);
    int y0 = (int)ysf;
    if (y0 > H0 - 2) y0 = H0 - 2;
    const float wy = ysf - (float)y0;
    const float* r0 = xc + y0 * H0;
    const float* r1 = r0 + H0;
    float res[4];
    #pragma unroll
    for (int i = 0; i < 4; i++) {
        const int W = wq * 4 + i;
        const float xsf = (float)W * (80.f / 323.f);
        int x0 = (int)xsf;
        if (x0 > H0 - 2) x0 = H0 - 2;
        const float wx = xsf - (float)x0;
        const float x00 = r0[x0], x01 = r0[x0 + 1];
        const float x10 = r1[x0], x11 = r1[x0 + 1];
        const float top = x00 + (x01 - x00) * wx;
        const float bot = x10 + (x11 - x10) * wx;
        const float xup = top + (bot - top) * wy;
        res[i] = xup + lam * (alp - xup) + gh * ahp;
    }
    *reinterpret_cast<float4*>(y_out + ((size_t)b * CIN + c) * NPH + H * HH + wq * 4) =
        make_float4(res[0], res[1], res[2], res[3]);
}

// ---------------------------------------------------------------------------
extern "C" void kernel_launch(void* const* d_in, const int* in_sizes, int n_in,
                              void* d_out, int out_size, void* d_ws, size_t ws_size,
                              hipStream_t stream)
{
    const float* x    = (const float*)d_in[0];
    const float* w1o  = (const float*)d_in[1];
    const float* b1o  = (const float*)d_in[2];
    const float* w2o  = (const float*)d_in[3];
    const float* b2o  = (const float*)d_in[4];
    const float* w1g  = (const float*)d_in[5];
    const float* b1g  = (const float*)d_in[6];
    const float* w2g  = (const float*)d_in[7];
    const float* b2g  = (const float*)d_in[8];
    const float* beta = (const float*)d_in[9];
    float* out = (float*)d_out;
    float* wsf = (float*)d_ws;

    // workspace layout (floats): ~16.5 MB total
    float* hid_o = wsf;
    float* hid_g = hid_o + (size_t)B_N * HIDC * NP;
    float* m_lp  = hid_g + (size_t)B_N * HIDC * NP;
    float* m_hp  = m_lp + (size_t)B_N * 9 * NP;
    float* g_buf = m_hp + (size_t)B_N * 9 * NP;
    float* a_lp  = g_buf + (size_t)B_N * NP;
    float* a_hp  = a_lp + (size_t)B_N * CIN * NP;

    // output layout: y [4,21,324,324], v [4,8,81,81], g_up [4,1,324,324]
    float* y_out = out;
    float* v_out = out + (size_t)B_N * CIN * NPH;
    float* gup   = v_out + (size_t)B_N * 8 * NP;

    k1_conv1<<<dim3(36, 6, B_N), 256, 0, stream>>>(x, w1o, b1o, w1g, b1g, hid_o, hid_g);
    k2_conv2_masks<<<dim3(121, B_N), 64, 0, stream>>>(hid_o, hid_g, w2o, b2o, w2g, b2g,
                                                      v_out, g_buf, m_lp, m_hp);
    k3_agg<<<dim3(121, B_N), 64, 0, stream>>>(x, m_lp, m_hp, a_lp, a_hp);
    k4_up<<<dim3(108, CIN + 1, B_N), 256, 0, stream>>>(x, g_buf, a_lp, a_hp, beta, y_out, gup);
}